// Round 1
// baseline (656.619 us; speedup 1.0000x reference)
//
#include <hip/hip_runtime.h>
#include <math.h>

// ---------------------------------------------------------------------------
// GATEncoder: 2x (GATConv(H=2,C=128) + exact GELU) + final projection.
// Strategy: CSR-by-dst built per call (hist+scan+scatter), then per-node
// wave-parallel online-softmax aggregation (gathers instead of atomics).
// fp32 everywhere (no fp32 MFMA on CDNA4; bf16 would risk the tolerance).
// ---------------------------------------------------------------------------

#define NEG_SLOPE 0.2f

// ---------------- GEMM: C[M,N] = A[M,K] @ B[K,N] (+bias) -------------------
// 64x64 tile, BK=16, 256 threads, 4x4 per thread. N%64==0, K%16==0 assumed.
#define BM 64
#define BN 64
#define BK 16

__global__ __launch_bounds__(256)
void gemm_kernel(const float* __restrict__ A, const float* __restrict__ B,
                 float* __restrict__ C, const float* __restrict__ bias,
                 int M, int N, int K)
{
    __shared__ float As[BK][BM + 4];   // padded, [k][m] layout
    __shared__ float Bs[BK][BN];       // [k][n] layout

    const int tid = threadIdx.x;
    const int r0 = blockIdx.y * BM;
    const int c0 = blockIdx.x * BN;
    const int tm = tid >> 4;           // 0..15 -> rows tm*4..tm*4+3
    const int tn = tid & 15;           // 0..15 -> cols tn*4..tn*4+3

    const int arow = tid >> 2;         // 0..63
    const int ak4  = (tid & 3) << 2;   // 0,4,8,12
    const int bk   = tid >> 4;         // 0..15
    const int bn4  = (tid & 15) << 2;  // 0..60

    float acc[4][4] = {};

    for (int kk = 0; kk < K; kk += BK) {
        float4 av = make_float4(0.f, 0.f, 0.f, 0.f);
        if (r0 + arow < M)
            av = *(const float4*)(A + (size_t)(r0 + arow) * K + kk + ak4);
        As[ak4 + 0][arow] = av.x;
        As[ak4 + 1][arow] = av.y;
        As[ak4 + 2][arow] = av.z;
        As[ak4 + 3][arow] = av.w;

        *(float4*)&Bs[bk][bn4] =
            *(const float4*)(B + (size_t)(kk + bk) * N + c0 + bn4);
        __syncthreads();

#pragma unroll
        for (int k = 0; k < BK; ++k) {
            float4 a = *(const float4*)&As[k][tm << 2];
            float4 b = *(const float4*)&Bs[k][tn << 2];
            acc[0][0] += a.x * b.x; acc[0][1] += a.x * b.y;
            acc[0][2] += a.x * b.z; acc[0][3] += a.x * b.w;
            acc[1][0] += a.y * b.x; acc[1][1] += a.y * b.y;
            acc[1][2] += a.y * b.z; acc[1][3] += a.y * b.w;
            acc[2][0] += a.z * b.x; acc[2][1] += a.z * b.y;
            acc[2][2] += a.z * b.z; acc[2][3] += a.z * b.w;
            acc[3][0] += a.w * b.x; acc[3][1] += a.w * b.y;
            acc[3][2] += a.w * b.z; acc[3][3] += a.w * b.w;
        }
        __syncthreads();
    }

    float4 bb = make_float4(0.f, 0.f, 0.f, 0.f);
    if (bias) bb = *(const float4*)(bias + c0 + (tn << 2));
#pragma unroll
    for (int i = 0; i < 4; ++i) {
        int row = r0 + (tm << 2) + i;
        if (row < M) {
            float4 o;
            o.x = acc[i][0] + bb.x; o.y = acc[i][1] + bb.y;
            o.z = acc[i][2] + bb.z; o.w = acc[i][3] + bb.w;
            *(float4*)(C + (size_t)row * N + c0 + (tn << 2)) = o;
        }
    }
}

// ------------- per-node attention coefficients a_src, a_dst ----------------
// one wave per node; lane l handles flat channels 4l..4l+3 of the 256-wide
// (H=2,C=128) row; half-wave reduce -> lanes 0 and 32 hold the head sums.
__global__ __launch_bounds__(256)
void compute_ab_kernel(const float* __restrict__ xl,
                       const float* __restrict__ att_s,
                       const float* __restrict__ att_d,
                       float* __restrict__ a_s, float* __restrict__ a_d, int n)
{
    const int wave = threadIdx.x >> 6;
    const int lane = threadIdx.x & 63;
    const int v = blockIdx.x * 4 + wave;
    if (v >= n) return;
    const int idx = lane << 2;
    float4 xv = *(const float4*)(xl + (size_t)v * 256 + idx);
    float4 s4 = *(const float4*)(att_s + idx);
    float4 d4 = *(const float4*)(att_d + idx);
    float ps = xv.x * s4.x + xv.y * s4.y + xv.z * s4.z + xv.w * s4.w;
    float pd = xv.x * d4.x + xv.y * d4.y + xv.z * d4.z + xv.w * d4.w;
#pragma unroll
    for (int off = 1; off < 32; off <<= 1) {
        ps += __shfl_xor(ps, off, 64);
        pd += __shfl_xor(pd, off, 64);
    }
    if ((lane & 31) == 0) {
        a_s[v * 2 + (lane >> 5)] = ps;
        a_d[v * 2 + (lane >> 5)] = pd;
    }
}

__device__ __forceinline__ float gelu_exact(float x)
{
    return 0.5f * x * (1.0f + erff(x * 0.7071067811865476f));
}

// ---------------- per-node online-softmax aggregation ----------------------
// one wave per node. lanes 0-31: head0 channels, 32-63: head1 channels
// (4 channels / lane). Self-loop seeds m/s/acc; edges gathered via CSR.
__global__ __launch_bounds__(256)
void gat_aggregate_kernel(const float* __restrict__ xl,
                          const float* __restrict__ a_s,
                          const float* __restrict__ a_d,
                          const int* __restrict__ rowptr,
                          const int* __restrict__ esrc,
                          const float* __restrict__ bias,
                          float* __restrict__ out, int n)
{
    const int wave = threadIdx.x >> 6;
    const int lane = threadIdx.x & 63;
    const int v = blockIdx.x * 4 + wave;
    if (v >= n) return;
    const int h = lane >> 5;

    const float adv = a_d[v * 2 + h];
    // self loop
    float e0 = a_s[v * 2 + h] + adv;
    e0 = e0 > 0.f ? e0 : NEG_SLOPE * e0;
    float m = e0, s = 1.0f;
    float4 acc = *(const float4*)(xl + (size_t)v * 256 + (lane << 2));

    const int beg = rowptr[v], end = rowptr[v + 1];
    for (int i = beg; i < end; ++i) {
        const int src = esrc[i];
        float sc = a_s[src * 2 + h] + adv;
        sc = sc > 0.f ? sc : NEG_SLOPE * sc;
        const float nm = fmaxf(m, sc);
        const float f = __expf(m - nm);
        const float w = __expf(sc - nm);
        const float4 xv = *(const float4*)(xl + (size_t)src * 256 + (lane << 2));
        s = s * f + w;
        acc.x = acc.x * f + w * xv.x;
        acc.y = acc.y * f + w * xv.y;
        acc.z = acc.z * f + w * xv.z;
        acc.w = acc.w * f + w * xv.w;
        m = nm;
    }

    const float inv = 1.0f / (s + 1e-16f);
    float4 r;
    r.x = acc.x * inv; r.y = acc.y * inv; r.z = acc.z * inv; r.w = acc.w * inv;
    // head mean: partner lane is lane^32
    float4 o;
    o.x = 0.5f * (r.x + __shfl_xor(r.x, 32, 64));
    o.y = 0.5f * (r.y + __shfl_xor(r.y, 32, 64));
    o.z = 0.5f * (r.z + __shfl_xor(r.z, 32, 64));
    o.w = 0.5f * (r.w + __shfl_xor(r.w, 32, 64));
    if (lane < 32) {
        float4 bb = *(const float4*)(bias + (lane << 2));
        o.x = gelu_exact(o.x + bb.x);
        o.y = gelu_exact(o.y + bb.y);
        o.z = gelu_exact(o.z + bb.z);
        o.w = gelu_exact(o.w + bb.w);
        *(float4*)(out + (size_t)v * 128 + (lane << 2)) = o;
    }
}

// ---------------------- CSR build (by dst) ---------------------------------
__global__ __launch_bounds__(256)
void hist_kernel(const int* __restrict__ ei, int* __restrict__ cnt, int E)
{
    int e = blockIdx.x * 256 + threadIdx.x;
    if (e < E) atomicAdd(&cnt[ei[E + e]], 1);
}

__global__ __launch_bounds__(1024)
void scan_kernel(const int* __restrict__ cnt, int* __restrict__ ptr, int n)
{
    __shared__ int sm[1024];
    __shared__ int carry;
    const int tid = threadIdx.x;
    if (tid == 0) carry = 0;
    __syncthreads();
    for (int base = 0; base < n; base += 1024) {
        int v = (base + tid < n) ? cnt[base + tid] : 0;
        sm[tid] = v;
        __syncthreads();
#pragma unroll
        for (int off = 1; off < 1024; off <<= 1) {
            int t = (tid >= off) ? sm[tid - off] : 0;
            __syncthreads();
            sm[tid] += t;
            __syncthreads();
        }
        if (base + tid < n) ptr[base + tid] = carry + sm[tid] - v;
        __syncthreads();
        if (tid == 0) carry += sm[1023];
        __syncthreads();
    }
    if (tid == 0) ptr[n] = carry;
}

__global__ __launch_bounds__(256)
void scatter_kernel(const int* __restrict__ ei, const int* __restrict__ ptr,
                    int* __restrict__ cnt, int* __restrict__ esrc, int E)
{
    int e = blockIdx.x * 256 + threadIdx.x;
    if (e < E) {
        int dst = ei[E + e];
        int src = ei[e];
        int pos = ptr[dst] + atomicAdd(&cnt[dst], 1);
        esrc[pos] = src;
    }
}

// ---------------------------------------------------------------------------
extern "C" void kernel_launch(void* const* d_in, const int* in_sizes, int n_in,
                              void* d_out, int out_size, void* d_ws, size_t ws_size,
                              hipStream_t stream)
{
    const float* x       = (const float*)d_in[0];
    const int*   ei      = (const int*)d_in[1];
    const float* W0      = (const float*)d_in[2];
    const float* att_s0  = (const float*)d_in[3];
    const float* att_d0  = (const float*)d_in[4];
    const float* b0      = (const float*)d_in[5];
    const float* W1      = (const float*)d_in[6];
    const float* att_s1  = (const float*)d_in[7];
    const float* att_d1  = (const float*)d_in[8];
    const float* b1      = (const float*)d_in[9];
    const float* pw      = (const float*)d_in[10];
    const float* pb      = (const float*)d_in[11];

    const int N = in_sizes[0] / 256;   // 50000
    const int E = in_sizes[1] / 2;     // 800000

    // workspace layout (fp32 unless noted)
    float* xl  = (float*)d_ws;                  // N*256
    float* h   = xl + (size_t)N * 256;          // N*128  (reused for layer2 out)
    float* a_s = h + (size_t)N * 128;           // N*2
    float* a_d = a_s + (size_t)N * 2;           // N*2
    int*   cnt = (int*)(a_d + (size_t)N * 2);   // N
    int*   ptr = cnt + N;                       // N+1
    int*   esr = ptr + (N + 1);                 // E

    const int ablk = (N + 3) / 4;               // 4 waves (nodes) per block
    const int eblk = (E + 255) / 256;
    const dim3 g256(256 / BN, (N + BM - 1) / BM);
    const dim3 g128(128 / BN, (N + BM - 1) / BM);

    // ---- CSR build (shared by both layers) ----
    hipMemsetAsync(cnt, 0, (size_t)N * sizeof(int), stream);
    hist_kernel<<<eblk, 256, 0, stream>>>(ei, cnt, E);
    scan_kernel<<<1, 1024, 0, stream>>>(cnt, ptr, N);
    hipMemsetAsync(cnt, 0, (size_t)N * sizeof(int), stream);
    scatter_kernel<<<eblk, 256, 0, stream>>>(ei, ptr, cnt, esr, E);

    // ---- layer 0 ----
    gemm_kernel<<<g256, 256, 0, stream>>>(x, W0, xl, nullptr, N, 256, 256);
    compute_ab_kernel<<<ablk, 256, 0, stream>>>(xl, att_s0, att_d0, a_s, a_d, N);
    gat_aggregate_kernel<<<ablk, 256, 0, stream>>>(xl, a_s, a_d, ptr, esr, b0, h, N);

    // ---- layer 1 ----
    gemm_kernel<<<g256, 256, 0, stream>>>(h, W1, xl, nullptr, N, 256, 128);
    compute_ab_kernel<<<ablk, 256, 0, stream>>>(xl, att_s1, att_d1, a_s, a_d, N);
    gat_aggregate_kernel<<<ablk, 256, 0, stream>>>(xl, a_s, a_d, ptr, esr, b1, h, N);

    // ---- projection ----
    gemm_kernel<<<g128, 256, 0, stream>>>(h, pw, (float*)d_out, pb, N, 128, 128);
}

// Round 2
// 558.587 us; speedup vs baseline: 1.1755x; 1.1755x over previous
//
#include <hip/hip_runtime.h>
#include <math.h>

// ---------------------------------------------------------------------------
// GATEncoder: 2x (GATConv(H=2,C=128) + exact GELU) + final projection.
// GEMMs: split-bf16 MFMA (hi/lo decomposition, 3 MFMA passes -> ~fp32 accuracy).
// Aggregation: CSR-by-dst + per-node wave online-softmax (unchanged this round).
// ---------------------------------------------------------------------------

#define NEG_SLOPE 0.2f

typedef __attribute__((ext_vector_type(8))) short bf16x8;
typedef __attribute__((ext_vector_type(8))) ushort u16x8;
typedef __attribute__((ext_vector_type(4))) float f32x4;

__device__ __forceinline__ void split_f32(float x, ushort& h, ushort& l)
{
    unsigned b = __float_as_uint(x);
    h = (ushort)(b >> 16);
    float xh = __uint_as_float(b & 0xffff0000u);
    l = (ushort)(__float_as_uint(x - xh) >> 16);
}

// ------------- weight prep: W[K][N] fp32 -> Bt_hi/Bt_lo [N][K] bf16 --------
__global__ __launch_bounds__(256)
void split_w_kernel(const float* __restrict__ W, ushort* __restrict__ Bth,
                    ushort* __restrict__ Btl, int K, int N)
{
    int t = blockIdx.x * 256 + threadIdx.x;
    if (t >= K * N) return;
    int k = t / N, n = t - k * N;
    ushort h, l;
    split_f32(W[t], h, l);
    Bth[(size_t)n * K + k] = h;
    Btl[(size_t)n * K + k] = l;
}

// ---------------- split-bf16 MFMA GEMM: C = A @ B (+bias) ------------------
// A: [M][K] fp32.  B pre-split/transposed: Bth/Btl [N][K] bf16.
// Block 128x128, 4 waves, each wave 64x64 (4x4 frags of 16x16x32).
// LDS frag layout [kplane][row][8]: 16-lane groups read 256B contiguous.
__global__ __launch_bounds__(256)
void mfma_gemm(const float* __restrict__ A,
               const ushort* __restrict__ Bth, const ushort* __restrict__ Btl,
               const float* __restrict__ bias,
               float* __restrict__ C, int M, int N, int K)
{
    __shared__ ushort Ah[4][128][8];
    __shared__ ushort Al[4][128][8];
    __shared__ ushort Bh[4][128][8];
    __shared__ ushort Bl[4][128][8];

    const int tid = threadIdx.x;
    const int r0 = blockIdx.y * 128;
    const int c0 = blockIdx.x * 128;
    const int w = tid >> 6, lane = tid & 63;
    const int wr = (w >> 1) * 64, wc = (w & 1) * 64;
    const int lr = lane & 15, kb = lane >> 4;

    const int sr = tid >> 1;      // staged row / col 0..127
    const int sh = tid & 1;       // k-half within 32-wide step
    const int p0 = sh * 2, p1 = sh * 2 + 1;

    f32x4 acc[4][4] = {};

    for (int kk = 0; kk < K; kk += 32) {
        // ---- stage A (fp32 -> hi/lo bf16) ----
        {
            const int row = r0 + sr;
            float4 v0, v1, v2, v3;
            if (row < M) {
                const float* p = A + (size_t)row * K + kk + sh * 16;
                v0 = *(const float4*)(p);
                v1 = *(const float4*)(p + 4);
                v2 = *(const float4*)(p + 8);
                v3 = *(const float4*)(p + 12);
            } else {
                v0 = v1 = v2 = v3 = make_float4(0.f, 0.f, 0.f, 0.f);
            }
            float v[16] = {v0.x, v0.y, v0.z, v0.w, v1.x, v1.y, v1.z, v1.w,
                           v2.x, v2.y, v2.z, v2.w, v3.x, v3.y, v3.z, v3.w};
            u16x8 h0, h1, l0, l1;
#pragma unroll
            for (int i = 0; i < 8; ++i) {
                ushort hh, ll;
                split_f32(v[i], hh, ll);     h0[i] = hh; l0[i] = ll;
                split_f32(v[8 + i], hh, ll); h1[i] = hh; l1[i] = ll;
            }
            *(u16x8*)&Ah[p0][sr][0] = h0;
            *(u16x8*)&Ah[p1][sr][0] = h1;
            *(u16x8*)&Al[p0][sr][0] = l0;
            *(u16x8*)&Al[p1][sr][0] = l1;
        }
        // ---- stage B (already split, just copy) ----
        {
            const ushort* ph = Bth + (size_t)(c0 + sr) * K + kk + sh * 16;
            const ushort* pl = Btl + (size_t)(c0 + sr) * K + kk + sh * 16;
            *(u16x8*)&Bh[p0][sr][0] = *(const u16x8*)(ph);
            *(u16x8*)&Bh[p1][sr][0] = *(const u16x8*)(ph + 8);
            *(u16x8*)&Bl[p0][sr][0] = *(const u16x8*)(pl);
            *(u16x8*)&Bl[p1][sr][0] = *(const u16x8*)(pl + 8);
        }
        __syncthreads();

        bf16x8 ah[4], al[4], bh[4], bl[4];
#pragma unroll
        for (int m = 0; m < 4; ++m) {
            ah[m] = *(const bf16x8*)&Ah[kb][wr + m * 16 + lr][0];
            al[m] = *(const bf16x8*)&Al[kb][wr + m * 16 + lr][0];
        }
#pragma unroll
        for (int n = 0; n < 4; ++n) {
            bh[n] = *(const bf16x8*)&Bh[kb][wc + n * 16 + lr][0];
            bl[n] = *(const bf16x8*)&Bl[kb][wc + n * 16 + lr][0];
        }
#pragma unroll
        for (int m = 0; m < 4; ++m)
#pragma unroll
            for (int n = 0; n < 4; ++n) {
                acc[m][n] = __builtin_amdgcn_mfma_f32_16x16x32_bf16(ah[m], bh[n], acc[m][n], 0, 0, 0);
                acc[m][n] = __builtin_amdgcn_mfma_f32_16x16x32_bf16(ah[m], bl[n], acc[m][n], 0, 0, 0);
                acc[m][n] = __builtin_amdgcn_mfma_f32_16x16x32_bf16(al[m], bh[n], acc[m][n], 0, 0, 0);
            }
        __syncthreads();
    }

    // epilogue: D row=(lane>>4)*4+j, col=lane&15 within each 16x16 frag
#pragma unroll
    for (int n = 0; n < 4; ++n) {
        const int col = c0 + wc + n * 16 + lr;
        const float bv = bias ? bias[col] : 0.f;
#pragma unroll
        for (int m = 0; m < 4; ++m) {
            const int rowb = r0 + wr + m * 16 + kb * 4;
#pragma unroll
            for (int j = 0; j < 4; ++j) {
                const int row = rowb + j;
                if (row < M) C[(size_t)row * N + col] = acc[m][n][j] + bv;
            }
        }
    }
}

// ------------- per-node attention coefficients a_src, a_dst ----------------
__global__ __launch_bounds__(256)
void compute_ab_kernel(const float* __restrict__ xl,
                       const float* __restrict__ att_s,
                       const float* __restrict__ att_d,
                       float* __restrict__ a_s, float* __restrict__ a_d, int n)
{
    const int wave = threadIdx.x >> 6;
    const int lane = threadIdx.x & 63;
    const int v = blockIdx.x * 4 + wave;
    if (v >= n) return;
    const int idx = lane << 2;
    float4 xv = *(const float4*)(xl + (size_t)v * 256 + idx);
    float4 s4 = *(const float4*)(att_s + idx);
    float4 d4 = *(const float4*)(att_d + idx);
    float ps = xv.x * s4.x + xv.y * s4.y + xv.z * s4.z + xv.w * s4.w;
    float pd = xv.x * d4.x + xv.y * d4.y + xv.z * d4.z + xv.w * d4.w;
#pragma unroll
    for (int off = 1; off < 32; off <<= 1) {
        ps += __shfl_xor(ps, off, 64);
        pd += __shfl_xor(pd, off, 64);
    }
    if ((lane & 31) == 0) {
        a_s[v * 2 + (lane >> 5)] = ps;
        a_d[v * 2 + (lane >> 5)] = pd;
    }
}

__device__ __forceinline__ float gelu_exact(float x)
{
    return 0.5f * x * (1.0f + erff(x * 0.7071067811865476f));
}

// ---------------- per-node online-softmax aggregation ----------------------
__global__ __launch_bounds__(256)
void gat_aggregate_kernel(const float* __restrict__ xl,
                          const float* __restrict__ a_s,
                          const float* __restrict__ a_d,
                          const int* __restrict__ rowptr,
                          const int* __restrict__ esrc,
                          const float* __restrict__ bias,
                          float* __restrict__ out, int n)
{
    const int wave = threadIdx.x >> 6;
    const int lane = threadIdx.x & 63;
    const int v = blockIdx.x * 4 + wave;
    if (v >= n) return;
    const int h = lane >> 5;

    const float adv = a_d[v * 2 + h];
    float e0 = a_s[v * 2 + h] + adv;
    e0 = e0 > 0.f ? e0 : NEG_SLOPE * e0;
    float m = e0, s = 1.0f;
    float4 acc = *(const float4*)(xl + (size_t)v * 256 + (lane << 2));

    const int beg = rowptr[v], end = rowptr[v + 1];
    for (int i = beg; i < end; ++i) {
        const int src = esrc[i];
        float sc = a_s[src * 2 + h] + adv;
        sc = sc > 0.f ? sc : NEG_SLOPE * sc;
        const float nm = fmaxf(m, sc);
        const float f = __expf(m - nm);
        const float w = __expf(sc - nm);
        const float4 xv = *(const float4*)(xl + (size_t)src * 256 + (lane << 2));
        s = s * f + w;
        acc.x = acc.x * f + w * xv.x;
        acc.y = acc.y * f + w * xv.y;
        acc.z = acc.z * f + w * xv.z;
        acc.w = acc.w * f + w * xv.w;
        m = nm;
    }

    const float inv = 1.0f / (s + 1e-16f);
    float4 r;
    r.x = acc.x * inv; r.y = acc.y * inv; r.z = acc.z * inv; r.w = acc.w * inv;
    float4 o;
    o.x = 0.5f * (r.x + __shfl_xor(r.x, 32, 64));
    o.y = 0.5f * (r.y + __shfl_xor(r.y, 32, 64));
    o.z = 0.5f * (r.z + __shfl_xor(r.z, 32, 64));
    o.w = 0.5f * (r.w + __shfl_xor(r.w, 32, 64));
    if (lane < 32) {
        float4 bb = *(const float4*)(bias + (lane << 2));
        o.x = gelu_exact(o.x + bb.x);
        o.y = gelu_exact(o.y + bb.y);
        o.z = gelu_exact(o.z + bb.z);
        o.w = gelu_exact(o.w + bb.w);
        *(float4*)(out + (size_t)v * 128 + (lane << 2)) = o;
    }
}

// ---------------------- CSR build (by dst) ---------------------------------
__global__ __launch_bounds__(256)
void hist_kernel(const int* __restrict__ ei, int* __restrict__ cnt, int E)
{
    int e = blockIdx.x * 256 + threadIdx.x;
    if (e < E) atomicAdd(&cnt[ei[E + e]], 1);
}

__global__ __launch_bounds__(1024)
void scan_kernel(const int* __restrict__ cnt, int* __restrict__ ptr, int n)
{
    __shared__ int sm[1024];
    __shared__ int carry;
    const int tid = threadIdx.x;
    if (tid == 0) carry = 0;
    __syncthreads();
    for (int base = 0; base < n; base += 1024) {
        int v = (base + tid < n) ? cnt[base + tid] : 0;
        sm[tid] = v;
        __syncthreads();
#pragma unroll
        for (int off = 1; off < 1024; off <<= 1) {
            int t = (tid >= off) ? sm[tid - off] : 0;
            __syncthreads();
            sm[tid] += t;
            __syncthreads();
        }
        if (base + tid < n) ptr[base + tid] = carry + sm[tid] - v;
        __syncthreads();
        if (tid == 0) carry += sm[1023];
        __syncthreads();
    }
    if (tid == 0) ptr[n] = carry;
}

__global__ __launch_bounds__(256)
void scatter_kernel(const int* __restrict__ ei, const int* __restrict__ ptr,
                    int* __restrict__ cnt, int* __restrict__ esrc, int E)
{
    int e = blockIdx.x * 256 + threadIdx.x;
    if (e < E) {
        int dst = ei[E + e];
        int src = ei[e];
        int pos = ptr[dst] + atomicAdd(&cnt[dst], 1);
        esrc[pos] = src;
    }
}

// ---------------------------------------------------------------------------
extern "C" void kernel_launch(void* const* d_in, const int* in_sizes, int n_in,
                              void* d_out, int out_size, void* d_ws, size_t ws_size,
                              hipStream_t stream)
{
    const float* x       = (const float*)d_in[0];
    const int*   ei      = (const int*)d_in[1];
    const float* W0      = (const float*)d_in[2];
    const float* att_s0  = (const float*)d_in[3];
    const float* att_d0  = (const float*)d_in[4];
    const float* b0      = (const float*)d_in[5];
    const float* W1      = (const float*)d_in[6];
    const float* att_s1  = (const float*)d_in[7];
    const float* att_d1  = (const float*)d_in[8];
    const float* b1      = (const float*)d_in[9];
    const float* pw      = (const float*)d_in[10];
    const float* pb      = (const float*)d_in[11];

    const int N = in_sizes[0] / 256;   // 50000
    const int E = in_sizes[1] / 2;     // 800000

    // workspace layout
    float*  xl  = (float*)d_ws;                  // N*256
    float*  h   = xl + (size_t)N * 256;          // N*128
    float*  a_s = h + (size_t)N * 128;           // N*2
    float*  a_d = a_s + (size_t)N * 2;           // N*2
    int*    cnt = (int*)(a_d + (size_t)N * 2);   // N
    int*    ptr = cnt + N;                       // N+1
    int*    esr = ptr + (N + 1);                 // E
    ushort* w0h = (ushort*)(esr + E);            // 256*256
    ushort* w0l = w0h + 256 * 256;
    ushort* w1h = w0l + 256 * 256;               // 128*256 (K=128,N=256)
    ushort* w1l = w1h + 128 * 256;
    ushort* pwh = w1l + 128 * 256;               // 128*128
    ushort* pwl = pwh + 128 * 128;

    const int ablk = (N + 3) / 4;
    const int eblk = (E + 255) / 256;
    const dim3 gL0(256 / 128, (N + 127) / 128);  // N_out=256
    const dim3 gL1(256 / 128, (N + 127) / 128);
    const dim3 gPj(128 / 128, (N + 127) / 128);  // N_out=128

    // ---- weight prep ----
    split_w_kernel<<<(256 * 256 + 255) / 256, 256, 0, stream>>>(W0, w0h, w0l, 256, 256);
    split_w_kernel<<<(128 * 256 + 255) / 256, 256, 0, stream>>>(W1, w1h, w1l, 128, 256);
    split_w_kernel<<<(128 * 128 + 255) / 256, 256, 0, stream>>>(pw, pwh, pwl, 128, 128);

    // ---- CSR build ----
    hipMemsetAsync(cnt, 0, (size_t)N * sizeof(int), stream);
    hist_kernel<<<eblk, 256, 0, stream>>>(ei, cnt, E);
    scan_kernel<<<1, 1024, 0, stream>>>(cnt, ptr, N);
    hipMemsetAsync(cnt, 0, (size_t)N * sizeof(int), stream);
    scatter_kernel<<<eblk, 256, 0, stream>>>(ei, ptr, cnt, esr, E);

    // ---- layer 0 ----
    mfma_gemm<<<gL0, 256, 0, stream>>>(x, w0h, w0l, nullptr, xl, N, 256, 256);
    compute_ab_kernel<<<ablk, 256, 0, stream>>>(xl, att_s0, att_d0, a_s, a_d, N);
    gat_aggregate_kernel<<<ablk, 256, 0, stream>>>(xl, a_s, a_d, ptr, esr, b0, h, N);

    // ---- layer 1 ----
    mfma_gemm<<<gL1, 256, 0, stream>>>(h, w1h, w1l, nullptr, xl, N, 256, 128);
    compute_ab_kernel<<<ablk, 256, 0, stream>>>(xl, att_s1, att_d1, a_s, a_d, N);
    gat_aggregate_kernel<<<ablk, 256, 0, stream>>>(xl, a_s, a_d, ptr, esr, b1, h, N);

    // ---- projection ----
    mfma_gemm<<<gPj, 256, 0, stream>>>(h, pwh, pwl, pb, (float*)d_out, N, 128, 128);
}